// Round 3
// baseline (567.917 us; speedup 1.0000x reference)
//
#include <hip/hip_runtime.h>
#include <math.h>

// Problem constants (fixed by reference)
#define BBATCH 16
#define NPC    2048          // points per cloud
#define KNBR   16            // knn k (self appended -> 17 edges)
#define CCH    64            // channels
#define NPTS   (BBATCH*NPC)  // 32768

// ---------------------------------------------------------------------------
// prep: Hd = W_dst@W_attn, Hs = W_src@W_attn, WP2 = W_pos@W_attn,
//       bb = b_pos@W_attn + b_attn.   (W_attn distributes over the subtraction
//       attention, removing the per-edge 64x64 matvec entirely.)
// ---------------------------------------------------------------------------
__global__ __launch_bounds__(256) void prep_kernel(
    const float* __restrict__ Wpos, const float* __restrict__ bpos,
    const float* __restrict__ Wattn, const float* __restrict__ battn,
    const float* __restrict__ Wsrc, const float* __restrict__ Wdst,
    float* __restrict__ Hd, float* __restrict__ Hs,
    float* __restrict__ WP2, float* __restrict__ bb) {
  int t = threadIdx.x;
  int c = t & 63, g = t >> 6;
  __shared__ float wa[64 * 64];
  for (int k = t; k < 4096; k += 256) wa[k] = Wattn[k];
  __syncthreads();
  for (int rr = 0; rr < 16; ++rr) {
    int r = g * 16 + rr;
    float ad = 0.f, as = 0.f;
    for (int d = 0; d < 64; ++d) {
      float w = wa[d * 64 + c];
      ad += Wdst[r * 64 + d] * w;
      as += Wsrc[r * 64 + d] * w;
    }
    Hd[r * 64 + c] = ad;
    Hs[r * 64 + c] = as;
  }
  if (g == 0) {
    for (int r = 0; r < 3; ++r) {
      float a = 0.f;
      for (int d = 0; d < 64; ++d) a += Wpos[r * 64 + d] * wa[d * 64 + c];
      WP2[r * 64 + c] = a;
    }
    float a = battn[c];
    for (int d = 0; d < 64; ++d) a += bpos[d] * wa[d * 64 + c];
    bb[c] = a;
  }
}

// ---------------------------------------------------------------------------
// gemm3: A2 = x@Hd, S2 = x@Hs, V = x@Wval   ([32768x64] @ [64x64], fp32)
// ---------------------------------------------------------------------------
__global__ __launch_bounds__(256) void gemm3_kernel(
    const float* __restrict__ x, const float* __restrict__ Hd,
    const float* __restrict__ Hs, const float* __restrict__ Wval,
    float* __restrict__ A2, float* __restrict__ S2, float* __restrict__ V) {
  int rb = blockIdx.x;
  int m = blockIdx.y;
  const float* W = (m == 0) ? Hd : (m == 1) ? Hs : Wval;
  float* O = (m == 0) ? A2 : (m == 1) ? S2 : V;
  int t = threadIdx.x, c = t & 63, g = t >> 6;
  __shared__ float xs[64 * 64];
  const float4* xg = (const float4*)(x + (size_t)rb * 64 * 64);
  float4* xls = (float4*)xs;
  for (int k = t; k < 1024; k += 256) xls[k] = xg[k];
  float wcol[64];
#pragma unroll
  for (int d = 0; d < 64; ++d) wcol[d] = W[d * 64 + c];
  __syncthreads();
  for (int rr = 0; rr < 16; ++rr) {
    int r = g * 16 + rr;
    const float4* xr = (const float4*)(xs + r * 64);
    float acc = 0.f;
#pragma unroll
    for (int d4 = 0; d4 < 16; ++d4) {
      float4 xv = xr[d4];
      acc += xv.x * wcol[4 * d4] + xv.y * wcol[4 * d4 + 1] +
             xv.z * wcol[4 * d4 + 2] + xv.w * wcol[4 * d4 + 3];
    }
    O[((size_t)rb * 64 + r) * 64 + c] = acc;
  }
}

// ---------------------------------------------------------------------------
// knn: exact 16-NN per target, one wave per target.  Distances in FP64
// (fp32->fp64 cvt is exact; __dmul_rn/__dadd_rn in numpy's ((dx^2+dy^2)+dz^2)
// order gives bit-identical fp64 d2 to a float64 numpy reference).  16 rounds
// of wave-wide lex-min extraction on (d2_bits64, idx) — fp64 bits are
// order-monotone for d2>=0; lower-index tie-break == lax.top_k semantics.
// ---------------------------------------------------------------------------
#define KNN_WAVES 8
__global__ __launch_bounds__(512) void knn_kernel(
    const float* __restrict__ pos, int* __restrict__ nbr) {
  __shared__ float px[NPC], py[NPC], pz[NPC];
  int t = threadIdx.x;
  int cloud = blockIdx.x >> 8;  // 4096 blocks, 256 per cloud
  const float* pc = pos + (size_t)cloud * NPC * 3;
  for (int k = t; k < NPC * 3; k += 512) {
    float v = pc[k];
    int p = k / 3, cc = k - 3 * p;
    if (cc == 0) px[p] = v;
    else if (cc == 1) py[p] = v;
    else pz[p] = v;
  }
  __syncthreads();

  int w = t >> 6, lane = t & 63;
  int gi = blockIdx.x * KNN_WAVES + w;  // global target
  int ti = gi & (NPC - 1);
  double tx = (double)px[ti], ty = (double)py[ti], tz = (double)pz[ti];

  unsigned long long kb[32];
#pragma unroll
  for (int c = 0; c < 32; ++c) {
    int j = c * 64 + lane;
    double dx = __dsub_rn(tx, (double)px[j]);
    double dy = __dsub_rn(ty, (double)py[j]);
    double dz = __dsub_rn(tz, (double)pz[j]);
    double d2 = __dadd_rn(__dadd_rn(__dmul_rn(dx, dx), __dmul_rn(dy, dy)),
                          __dmul_rn(dz, dz));
    unsigned long long b = (unsigned long long)__double_as_longlong(d2);
    if (j == ti) b = 0xFFFFFFFFFFFFFFFFull;  // self excluded
    kb[c] = b;
  }

  for (int r = 0; r < KNBR; ++r) {
    // lane-local lex-min (static indices only)
    unsigned long long lm = kb[0];
    int cm = 0;
#pragma unroll
    for (int c = 1; c < 32; ++c) {
      if (kb[c] < lm) { lm = kb[c]; cm = c; }
    }
    unsigned long long gb = lm;
    int gj = cm * 64 + lane;
    // wave-wide lex-min over (d2bits, idx)
#pragma unroll
    for (int d = 32; d >= 1; d >>= 1) {
      unsigned long long ob = __shfl_xor(gb, d);
      int oj = __shfl_xor(gj, d);
      if (ob < gb || (ob == gb && oj < gj)) { gb = ob; gj = oj; }
    }
    // clear the winning candidate
#pragma unroll
    for (int c = 0; c < 32; ++c) {
      if (c * 64 + lane == gj) kb[c] = 0xFFFFFFFFFFFFFFFFull;
    }
    if (lane == 0) nbr[(size_t)gi * KNBR + r] = gj;
  }
}

// ---------------------------------------------------------------------------
// edge: per target (1 wave, lane = channel): logits via precomputed A2/S2/WP2,
// delta via W_pos; 17-way softmax + weighted sum, self loop last (= ref order).
// ---------------------------------------------------------------------------
__global__ __launch_bounds__(256) void edge_kernel(
    const float* __restrict__ pos, const int* __restrict__ nbr,
    const float* __restrict__ A2, const float* __restrict__ S2,
    const float* __restrict__ V, const float* __restrict__ WP2,
    const float* __restrict__ bbv, const float* __restrict__ Wpos,
    const float* __restrict__ bpos, float* __restrict__ out) {
  int t = threadIdx.x, w = t >> 6, c = t & 63;
  int gi = blockIdx.x * 4 + w;
  int cloudbase = gi & ~(NPC - 1);
  float pix = pos[(size_t)gi * 3], piy = pos[(size_t)gi * 3 + 1],
        piz = pos[(size_t)gi * 3 + 2];
  float a2 = A2[(size_t)gi * 64 + c];
  float wp0 = WP2[c], wp1 = WP2[64 + c], wp2 = WP2[128 + c], bbc = bbv[c];
  float u0 = Wpos[c], u1 = Wpos[64 + c], u2 = Wpos[128 + c], bpc = bpos[c];

  float lg[17], vl[17];
#pragma unroll
  for (int e = 0; e < 17; ++e) {
    int j = (e < 16) ? nbr[(size_t)gi * KNBR + e] : (gi & (NPC - 1));
    int jg = cloudbase + j;
    float dx = pix - pos[(size_t)jg * 3];
    float dy = piy - pos[(size_t)jg * 3 + 1];
    float dz = piz - pos[(size_t)jg * 3 + 2];
    float s2 = S2[(size_t)jg * 64 + c];
    float v = V[(size_t)jg * 64 + c];
    lg[e] = a2 - s2 + dx * wp0 + dy * wp1 + dz * wp2 + bbc;
    vl[e] = v + dx * u0 + dy * u1 + dz * u2 + bpc;
  }
  float mx = lg[0];
#pragma unroll
  for (int e = 1; e < 17; ++e) mx = fmaxf(mx, lg[e]);
  float den = 0.f, acc = 0.f;
#pragma unroll
  for (int e = 0; e < 17; ++e) {
    float wgt = __expf(lg[e] - mx);
    den += wgt;
    acc += wgt * vl[e];
  }
  out[(size_t)gi * 64 + c] = acc / den;
}

// ---------------------------------------------------------------------------
extern "C" void kernel_launch(void* const* d_in, const int* in_sizes, int n_in,
                              void* d_out, int out_size, void* d_ws, size_t ws_size,
                              hipStream_t stream) {
  const float* x     = (const float*)d_in[0];
  const float* pos   = (const float*)d_in[1];
  // d_in[2] = batch (contiguous equal clouds; unused)
  const float* Wpos  = (const float*)d_in[3];
  const float* bpos  = (const float*)d_in[4];
  const float* Wattn = (const float*)d_in[5];
  const float* battn = (const float*)d_in[6];
  const float* Wval  = (const float*)d_in[7];
  const float* Wsrc  = (const float*)d_in[8];
  const float* Wdst  = (const float*)d_in[9];

  float* ws  = (float*)d_ws;
  float* A2  = ws;                       // 32768*64
  float* S2  = A2 + (size_t)NPTS * 64;   // 32768*64
  float* V   = S2 + (size_t)NPTS * 64;   // 32768*64
  float* Hd  = V + (size_t)NPTS * 64;    // 64*64
  float* Hs  = Hd + 4096;                // 64*64
  float* WP2 = Hs + 4096;                // 3*64
  float* bb  = WP2 + 192;                // 64
  int*   nbr = (int*)(bb + 64);          // 32768*16 ints
  float* out = (float*)d_out;

  prep_kernel<<<1, 256, 0, stream>>>(Wpos, bpos, Wattn, battn, Wsrc, Wdst,
                                     Hd, Hs, WP2, bb);
  knn_kernel<<<NPTS / KNN_WAVES, 512, 0, stream>>>(pos, nbr);
  gemm3_kernel<<<dim3(NPTS / 64, 3), 256, 0, stream>>>(x, Hd, Hs, Wval, A2, S2, V);
  edge_kernel<<<NPTS / 4, 256, 0, stream>>>(pos, nbr, A2, S2, V, WP2, bb,
                                            Wpos, bpos, out);
}

// Round 4
// 285.536 us; speedup vs baseline: 1.9890x; 1.9890x over previous
//
#include <hip/hip_runtime.h>
#include <math.h>

// Problem constants (fixed by reference)
#define BBATCH 16
#define NPC    2048          // points per cloud
#define KNBR   16            // knn k (self appended -> 17 edges)
#define CCH    64            // channels
#define NPTS   (BBATCH*NPC)  // 32768

// ---------------------------------------------------------------------------
// prep: Hd = W_dst@W_attn, Hs = W_src@W_attn, WP2 = W_pos@W_attn,
//       bb = b_pos@W_attn + b_attn.
// ---------------------------------------------------------------------------
__global__ __launch_bounds__(256) void prep_kernel(
    const float* __restrict__ Wpos, const float* __restrict__ bpos,
    const float* __restrict__ Wattn, const float* __restrict__ battn,
    const float* __restrict__ Wsrc, const float* __restrict__ Wdst,
    float* __restrict__ Hd, float* __restrict__ Hs,
    float* __restrict__ WP2, float* __restrict__ bb) {
  int t = threadIdx.x;
  int c = t & 63, g = t >> 6;
  __shared__ float wa[64 * 64];
  for (int k = t; k < 4096; k += 256) wa[k] = Wattn[k];
  __syncthreads();
  for (int rr = 0; rr < 16; ++rr) {
    int r = g * 16 + rr;
    float ad = 0.f, as = 0.f;
    for (int d = 0; d < 64; ++d) {
      float w = wa[d * 64 + c];
      ad += Wdst[r * 64 + d] * w;
      as += Wsrc[r * 64 + d] * w;
    }
    Hd[r * 64 + c] = ad;
    Hs[r * 64 + c] = as;
  }
  if (g == 0) {
    for (int r = 0; r < 3; ++r) {
      float a = 0.f;
      for (int d = 0; d < 64; ++d) a += Wpos[r * 64 + d] * wa[d * 64 + c];
      WP2[r * 64 + c] = a;
    }
    float a = battn[c];
    for (int d = 0; d < 64; ++d) a += bpos[d] * wa[d * 64 + c];
    bb[c] = a;
  }
}

// ---------------------------------------------------------------------------
// gemm3: A2 = x@Hd, S2 = x@Hs, V = x@Wval   ([32768x64] @ [64x64], fp32)
// ---------------------------------------------------------------------------
__global__ __launch_bounds__(256) void gemm3_kernel(
    const float* __restrict__ x, const float* __restrict__ Hd,
    const float* __restrict__ Hs, const float* __restrict__ Wval,
    float* __restrict__ A2, float* __restrict__ S2, float* __restrict__ V) {
  int rb = blockIdx.x;
  int m = blockIdx.y;
  const float* W = (m == 0) ? Hd : (m == 1) ? Hs : Wval;
  float* O = (m == 0) ? A2 : (m == 1) ? S2 : V;
  int t = threadIdx.x, c = t & 63, g = t >> 6;
  __shared__ float xs[64 * 64];
  const float4* xg = (const float4*)(x + (size_t)rb * 64 * 64);
  float4* xls = (float4*)xs;
  for (int k = t; k < 1024; k += 256) xls[k] = xg[k];
  float wcol[64];
#pragma unroll
  for (int d = 0; d < 64; ++d) wcol[d] = W[d * 64 + c];
  __syncthreads();
  for (int rr = 0; rr < 16; ++rr) {
    int r = g * 16 + rr;
    const float4* xr = (const float4*)(xs + r * 64);
    float acc = 0.f;
#pragma unroll
    for (int d4 = 0; d4 < 16; ++d4) {
      float4 xv = xr[d4];
      acc += xv.x * wcol[4 * d4] + xv.y * wcol[4 * d4 + 1] +
             xv.z * wcol[4 * d4 + 2] + xv.w * wcol[4 * d4 + 3];
    }
    O[((size_t)rb * 64 + r) * 64 + c] = acc;
  }
}

// ---------------------------------------------------------------------------
// knn: exact fp64 16-NN per target, one wave per target.
// Phase A: fp32 d^2 -> 8-bit exponent bucket (bits>>20). fp32 rounding error
//   (~20 ulps) << bucket width (2^20 ulps), so {bucket <= T+1} provably
//   contains all true fp64 top-16.
// Phase B: binary search (ballot-count) for bucket T of the 16th value.
// Phase C: gather candidates with bucket <= T+1 to per-wave LDS buffer.
// Phase D: fp64 d^2 (bit-matching numpy f64: ((dx^2+dy^2)+dz^2)) on the
//   candidates, 64-wide bitonic sort by (d2bits, idx); lanes 0..15 emit.
//   (Lex order on (d2,idx) == lax.top_k tie semantics. Output order doesn't
//   affect the softmax beyond fp32 rounding anyway.)
// Rare n>64 fallback: extraction rounds over the buffer (<=512).
// ---------------------------------------------------------------------------
#define KNN_WAVES 8
#define BUFCAP 512
__global__ __launch_bounds__(512) void knn_kernel(
    const float* __restrict__ pos, int* __restrict__ nbr) {
  __shared__ float px[NPC], py[NPC], pz[NPC];
  __shared__ unsigned short buf[KNN_WAVES][BUFCAP];
  __shared__ int ctr[KNN_WAVES];

  int t = threadIdx.x;
  int cloud = blockIdx.x >> 8;  // 4096 blocks, 256 per cloud
  const float* pc = pos + (size_t)cloud * NPC * 3;
  for (int k = t; k < NPC * 3; k += 512) {
    float v = pc[k];
    int p = k / 3, cc = k - 3 * p;
    if (cc == 0) px[p] = v;
    else if (cc == 1) py[p] = v;
    else pz[p] = v;
  }
  int w = t >> 6, lane = t & 63;
  if (lane == 0) ctr[w] = 0;
  __syncthreads();

  int gi = blockIdx.x * KNN_WAVES + w;  // global target
  int ti = gi & (NPC - 1);
  float tx = px[ti], ty = py[ti], tz = pz[ti];

  // Phase A: fp32 buckets (self forced to 255 so it never counts low)
  int bkt[32];
#pragma unroll
  for (int c = 0; c < 32; ++c) {
    int j = c * 64 + lane;
    float dx = tx - px[j], dy = ty - py[j], dz = tz - pz[j];
    float d2 = dx * dx + dy * dy + dz * dz;
    int b = (int)(__float_as_uint(d2) >> 20) - 896;
    b = max(0, min(255, b));
    if (j == ti) b = 255;
    bkt[c] = b;
  }

  // Phase B: smallest T with count(bkt<=T) >= 16
  int lo = 0, hi = 255;
  for (int it = 0; it < 8; ++it) {
    int mid = (lo + hi) >> 1;
    int cnt = 0;
#pragma unroll
    for (int c = 0; c < 32; ++c)
      cnt += (int)__popcll(__ballot(bkt[c] <= mid));
    if (cnt >= 16) hi = mid; else lo = mid + 1;
  }
  int Tp1 = min(hi + 1, 255);

  // Phase C: gather superset
#pragma unroll
  for (int c = 0; c < 32; ++c) {
    if (bkt[c] <= Tp1) {
      int p = atomicAdd(&ctr[w], 1);
      if (p < BUFCAP) buf[w][p] = (unsigned short)(c * 64 + lane);
    }
  }
  __syncthreads();

  int n = min(ctr[w], BUFCAP);
  double txd = (double)tx, tyd = (double)ty, tzd = (double)tz;

  if (n <= 64) {
    // Phase D: one candidate per lane, fp64 key, bitonic sort 64
    unsigned long long gb = 0xFFFFFFFFFFFFFFFFull;
    int gj = 0x40000000 + lane;  // distinct pad ids
    if (lane < n) {
      int j = buf[w][lane];
      if (j != ti) {
        double dx = __dsub_rn(txd, (double)px[j]);
        double dy = __dsub_rn(tyd, (double)py[j]);
        double dz = __dsub_rn(tzd, (double)pz[j]);
        double d2 = __dadd_rn(__dadd_rn(__dmul_rn(dx, dx), __dmul_rn(dy, dy)),
                              __dmul_rn(dz, dz));
        gb = (unsigned long long)__double_as_longlong(d2);
        gj = j;
      }
    }
    for (int k = 2; k <= 64; k <<= 1) {
      for (int jj = k >> 1; jj > 0; jj >>= 1) {
        unsigned long long ob = __shfl_xor(gb, jj);
        int oj = __shfl_xor(gj, jj);
        bool keepmin = (((lane & k) == 0) == ((lane & jj) == 0));
        bool less = (ob < gb) || (ob == gb && oj < gj);
        if (keepmin == less) { gb = ob; gj = oj; }
      }
    }
    if (lane < KNBR) nbr[(size_t)gi * KNBR + lane] = gj;
  } else {
    // rare fallback: extraction over buffered set (n <= 512)
    unsigned long long kb2[8];
    int id2[8];
#pragma unroll
    for (int r = 0; r < 8; ++r) {
      int e = r * 64 + lane;
      kb2[r] = 0xFFFFFFFFFFFFFFFFull;
      id2[r] = 0x40000000 + e;
      if (e < n) {
        int j = buf[w][e];
        if (j != ti) {
          double dx = __dsub_rn(txd, (double)px[j]);
          double dy = __dsub_rn(tyd, (double)py[j]);
          double dz = __dsub_rn(tzd, (double)pz[j]);
          double d2 = __dadd_rn(__dadd_rn(__dmul_rn(dx, dx), __dmul_rn(dy, dy)),
                                __dmul_rn(dz, dz));
          kb2[r] = (unsigned long long)__double_as_longlong(d2);
          id2[r] = j;
        }
      }
    }
    for (int r = 0; r < KNBR; ++r) {
      unsigned long long lb = kb2[0];
      int lj = id2[0];
#pragma unroll
      for (int c = 1; c < 8; ++c)
        if (kb2[c] < lb || (kb2[c] == lb && id2[c] < lj)) {
          lb = kb2[c]; lj = id2[c];
        }
      unsigned long long gb2 = lb;
      int gj2 = lj;
#pragma unroll
      for (int d = 32; d >= 1; d >>= 1) {
        unsigned long long ob = __shfl_xor(gb2, d);
        int oj = __shfl_xor(gj2, d);
        if (ob < gb2 || (ob == gb2 && oj < gj2)) { gb2 = ob; gj2 = oj; }
      }
#pragma unroll
      for (int c = 0; c < 8; ++c)
        if (id2[c] == gj2) kb2[c] = 0xFFFFFFFFFFFFFFFFull;
      if (lane == 0) nbr[(size_t)gi * KNBR + r] = gj2;
    }
  }
}

// ---------------------------------------------------------------------------
// edge: per target (1 wave, lane = channel): logits via precomputed A2/S2/WP2,
// delta via W_pos; 17-way softmax + weighted sum, self loop last.
// ---------------------------------------------------------------------------
__global__ __launch_bounds__(256) void edge_kernel(
    const float* __restrict__ pos, const int* __restrict__ nbr,
    const float* __restrict__ A2, const float* __restrict__ S2,
    const float* __restrict__ V, const float* __restrict__ WP2,
    const float* __restrict__ bbv, const float* __restrict__ Wpos,
    const float* __restrict__ bpos, float* __restrict__ out) {
  int t = threadIdx.x, w = t >> 6, c = t & 63;
  int gi = blockIdx.x * 4 + w;
  int cloudbase = gi & ~(NPC - 1);
  float pix = pos[(size_t)gi * 3], piy = pos[(size_t)gi * 3 + 1],
        piz = pos[(size_t)gi * 3 + 2];
  float a2 = A2[(size_t)gi * 64 + c];
  float wp0 = WP2[c], wp1 = WP2[64 + c], wp2 = WP2[128 + c], bbc = bbv[c];
  float u0 = Wpos[c], u1 = Wpos[64 + c], u2 = Wpos[128 + c], bpc = bpos[c];

  float lg[17], vl[17];
#pragma unroll
  for (int e = 0; e < 17; ++e) {
    int j = (e < 16) ? nbr[(size_t)gi * KNBR + e] : (gi & (NPC - 1));
    int jg = cloudbase + j;
    float dx = pix - pos[(size_t)jg * 3];
    float dy = piy - pos[(size_t)jg * 3 + 1];
    float dz = piz - pos[(size_t)jg * 3 + 2];
    float s2 = S2[(size_t)jg * 64 + c];
    float v = V[(size_t)jg * 64 + c];
    lg[e] = a2 - s2 + dx * wp0 + dy * wp1 + dz * wp2 + bbc;
    vl[e] = v + dx * u0 + dy * u1 + dz * u2 + bpc;
  }
  float mx = lg[0];
#pragma unroll
  for (int e = 1; e < 17; ++e) mx = fmaxf(mx, lg[e]);
  float den = 0.f, acc = 0.f;
#pragma unroll
  for (int e = 0; e < 17; ++e) {
    float wgt = __expf(lg[e] - mx);
    den += wgt;
    acc += wgt * vl[e];
  }
  out[(size_t)gi * 64 + c] = acc / den;
}

// ---------------------------------------------------------------------------
extern "C" void kernel_launch(void* const* d_in, const int* in_sizes, int n_in,
                              void* d_out, int out_size, void* d_ws, size_t ws_size,
                              hipStream_t stream) {
  const float* x     = (const float*)d_in[0];
  const float* pos   = (const float*)d_in[1];
  // d_in[2] = batch (contiguous equal clouds; unused)
  const float* Wpos  = (const float*)d_in[3];
  const float* bpos  = (const float*)d_in[4];
  const float* Wattn = (const float*)d_in[5];
  const float* battn = (const float*)d_in[6];
  const float* Wval  = (const float*)d_in[7];
  const float* Wsrc  = (const float*)d_in[8];
  const float* Wdst  = (const float*)d_in[9];

  float* ws  = (float*)d_ws;
  float* A2  = ws;                       // 32768*64
  float* S2  = A2 + (size_t)NPTS * 64;   // 32768*64
  float* V   = S2 + (size_t)NPTS * 64;   // 32768*64
  float* Hd  = V + (size_t)NPTS * 64;    // 64*64
  float* Hs  = Hd + 4096;                // 64*64
  float* WP2 = Hs + 4096;                // 3*64
  float* bb  = WP2 + 192;                // 64
  int*   nbr = (int*)(bb + 64);          // 32768*16 ints
  float* out = (float*)d_out;

  prep_kernel<<<1, 256, 0, stream>>>(Wpos, bpos, Wattn, battn, Wsrc, Wdst,
                                     Hd, Hs, WP2, bb);
  knn_kernel<<<NPTS / KNN_WAVES, 512, 0, stream>>>(pos, nbr);
  gemm3_kernel<<<dim3(NPTS / 64, 3), 256, 0, stream>>>(x, Hd, Hs, Wval, A2, S2, V);
  edge_kernel<<<NPTS / 4, 256, 0, stream>>>(pos, nbr, A2, S2, V, WP2, bb,
                                            Wpos, bpos, out);
}

// Round 5
// 233.538 us; speedup vs baseline: 2.4318x; 1.2227x over previous
//
#include <hip/hip_runtime.h>
#include <math.h>

// Problem constants (fixed by reference)
#define BBATCH 16
#define NPC    2048          // points per cloud
#define KNBR   16            // knn k (self appended -> 17 edges)
#define NPTS   (BBATCH*NPC)  // 32768

#define NGEMM     128        // gemm blocks (256 rows each)
#define NKNN      2048       // knn blocks (16 targets each)
#define KNN_WAVES 16
#define BUFCAP    512

// ---------------------------------------------------------------------------
// fused1: one kernel, three independent block families (no cross-block deps):
//   block 0          : WP2 = Wpos@Wattn, bb = bpos@Wattn + battn (for edge)
//   blocks 1..128    : V = x@Wval, A2 = (x@Wdst)@Wattn, S2 = (x@Wsrc)@Wattn
//                      (chained in-block: Hd/Hs built in LDS once per block,
//                       removing the prep->gemm kernel dependency)
//   blocks 129..2176 : exact fp64 16-NN, 16 targets per 1024-thread block
// LDS overlay (64KB): knn: pos4 32K | buf 16K | ctr. gemm: 4 x 16K regions.
// ---------------------------------------------------------------------------
__global__ __launch_bounds__(1024) void fused1_kernel(
    const float* __restrict__ pos, const float* __restrict__ x,
    const float* __restrict__ Wpos, const float* __restrict__ bpos,
    const float* __restrict__ Wattn, const float* __restrict__ battn,
    const float* __restrict__ Wval, const float* __restrict__ Wsrc,
    const float* __restrict__ Wdst,
    int* __restrict__ nbr, float* __restrict__ A2, float* __restrict__ S2,
    float* __restrict__ V, float* __restrict__ WP2, float* __restrict__ bb) {
  __shared__ __align__(16) char smem[65536];
  int t = threadIdx.x;
  int bid = blockIdx.x;

  if (bid == 0) {
    // ---- prep-lite (consumed only by the edge kernel, launched after) ----
    if (t < 64) {
      int c = t;
      for (int r = 0; r < 3; ++r) {
        float a = 0.f;
        for (int d = 0; d < 64; ++d) a += Wpos[r * 64 + d] * Wattn[d * 64 + c];
        WP2[r * 64 + c] = a;
      }
      float a = battn[c];
      for (int d = 0; d < 64; ++d) a += bpos[d] * Wattn[d * 64 + c];
      bb[c] = a;
    }
    return;
  }

  if (bid <= NGEMM) {
    // ---- gemm family: 256 rows per block ----
    int gb = bid - 1;
    float* R0 = (float*)smem;             // staging: Wdst / Wsrc / x tiles
    float* R1 = (float*)(smem + 16384);   // Hd = Wdst@Wattn
    float* R2 = (float*)(smem + 32768);   // Hs = Wsrc@Wattn
    float* R3 = (float*)(smem + 49152);   // Wattn, then Wval
    float4* R04 = (float4*)R0;
    float4* R34 = (float4*)R3;
    int c = t & 63, g = t >> 6;

    R34[t] = ((const float4*)Wattn)[t];
    R04[t] = ((const float4*)Wdst)[t];
    __syncthreads();
    {  // Hd -> R1
      float a0 = 0, a1 = 0, a2 = 0, a3 = 0;
      for (int k = 0; k < 64; ++k) {
        float w = R3[k * 64 + c];
        a0 += R0[(g * 4 + 0) * 64 + k] * w;
        a1 += R0[(g * 4 + 1) * 64 + k] * w;
        a2 += R0[(g * 4 + 2) * 64 + k] * w;
        a3 += R0[(g * 4 + 3) * 64 + k] * w;
      }
      R1[(g * 4 + 0) * 64 + c] = a0; R1[(g * 4 + 1) * 64 + c] = a1;
      R1[(g * 4 + 2) * 64 + c] = a2; R1[(g * 4 + 3) * 64 + c] = a3;
    }
    __syncthreads();
    R04[t] = ((const float4*)Wsrc)[t];
    __syncthreads();
    {  // Hs -> R2
      float a0 = 0, a1 = 0, a2 = 0, a3 = 0;
      for (int k = 0; k < 64; ++k) {
        float w = R3[k * 64 + c];
        a0 += R0[(g * 4 + 0) * 64 + k] * w;
        a1 += R0[(g * 4 + 1) * 64 + k] * w;
        a2 += R0[(g * 4 + 2) * 64 + k] * w;
        a3 += R0[(g * 4 + 3) * 64 + k] * w;
      }
      R2[(g * 4 + 0) * 64 + c] = a0; R2[(g * 4 + 1) * 64 + c] = a1;
      R2[(g * 4 + 2) * 64 + c] = a2; R2[(g * 4 + 3) * 64 + c] = a3;
    }
    __syncthreads();
    R34[t] = ((const float4*)Wval)[t];  // Wattn dead, reuse R3 for Wval
    __syncthreads();

    for (int tile = 0; tile < 4; ++tile) {
      int R = gb * 256 + tile * 64;
      R04[t] = ((const float4*)(x + (size_t)R * 64))[t];
      __syncthreads();
      float v0 = 0, v1 = 0, v2 = 0, v3 = 0;
      float a0 = 0, a1 = 0, a2 = 0, a3 = 0;
      float s0 = 0, s1 = 0, s2 = 0, s3 = 0;
      const float4* xr0 = (const float4*)(R0 + (g * 4 + 0) * 64);
      const float4* xr1 = (const float4*)(R0 + (g * 4 + 1) * 64);
      const float4* xr2 = (const float4*)(R0 + (g * 4 + 2) * 64);
      const float4* xr3 = (const float4*)(R0 + (g * 4 + 3) * 64);
#pragma unroll 4
      for (int k4 = 0; k4 < 16; ++k4) {
        float4 q0 = xr0[k4], q1 = xr1[k4], q2 = xr2[k4], q3 = xr3[k4];
#pragma unroll
        for (int kk = 0; kk < 4; ++kk) {
          int k = k4 * 4 + kk;
          float wv = R3[k * 64 + c];
          float wa = R1[k * 64 + c];
          float ws = R2[k * 64 + c];
          float e0 = (kk == 0) ? q0.x : (kk == 1) ? q0.y : (kk == 2) ? q0.z : q0.w;
          float e1 = (kk == 0) ? q1.x : (kk == 1) ? q1.y : (kk == 2) ? q1.z : q1.w;
          float e2 = (kk == 0) ? q2.x : (kk == 1) ? q2.y : (kk == 2) ? q2.z : q2.w;
          float e3 = (kk == 0) ? q3.x : (kk == 1) ? q3.y : (kk == 2) ? q3.z : q3.w;
          v0 += e0 * wv; v1 += e1 * wv; v2 += e2 * wv; v3 += e3 * wv;
          a0 += e0 * wa; a1 += e1 * wa; a2 += e2 * wa; a3 += e3 * wa;
          s0 += e0 * ws; s1 += e1 * ws; s2 += e2 * ws; s3 += e3 * ws;
        }
      }
      size_t o0 = ((size_t)R + g * 4 + 0) * 64 + c;
      V[o0] = v0; A2[o0] = a0; S2[o0] = s0;
      size_t o1 = o0 + 64;  V[o1] = v1; A2[o1] = a1; S2[o1] = s1;
      size_t o2 = o0 + 128; V[o2] = v2; A2[o2] = a2; S2[o2] = s2;
      size_t o3 = o0 + 192; V[o3] = v3; A2[o3] = a3; S2[o3] = s3;
      __syncthreads();  // protect R0 before next tile's staging
    }
    return;
  }

  // ---- knn family ----
  int kb = bid - (NGEMM + 1);  // 0..2047
  float4* pos4 = (float4*)smem;                               // 2048 * 16B
  unsigned short* buf = (unsigned short*)(smem + 32768);      // 16 * 512 u16
  int* ctr = (int*)(smem + 32768 + 16384);                    // 16 ints

  int cloud = kb >> 7;  // 128 blocks per cloud
  const float* pc = pos + (size_t)cloud * NPC * 3;
  for (int p = t; p < NPC; p += 1024)
    pos4[p] = make_float4(pc[3 * p], pc[3 * p + 1], pc[3 * p + 2], 0.f);
  int w = t >> 6, lane = t & 63;
  if (lane == 0) ctr[w] = 0;
  __syncthreads();

  int gi = kb * KNN_WAVES + w;  // global target
  int ti = gi & (NPC - 1);
  float4 tp = pos4[ti];
  float tx = tp.x, ty = tp.y, tz = tp.z;

  // Phase A: fp32 d^2 -> 8-bit exponent bucket; self forced high.
  int bkt[32];
#pragma unroll
  for (int c = 0; c < 32; ++c) {
    int j = c * 64 + lane;
    float4 q = pos4[j];
    float dx = tx - q.x, dy = ty - q.y, dz = tz - q.z;
    float d2 = dx * dx + dy * dy + dz * dz;
    int b = (int)(__float_as_uint(d2) >> 20) - 896;
    b = max(0, min(255, b));
    if (j == ti) b = 255;
    bkt[c] = b;
  }

  // Phase B: binary search for smallest T with count(bkt<=T) >= 16
  int lo = 0, hi = 255;
  for (int it = 0; it < 8; ++it) {
    int mid = (lo + hi) >> 1;
    int cnt = 0;
#pragma unroll
    for (int c = 0; c < 32; ++c)
      cnt += (int)__popcll(__ballot(bkt[c] <= mid));
    if (cnt >= 16) hi = mid; else lo = mid + 1;
  }
  int Tp1 = min(hi + 1, 255);

  // Phase C: gather superset (bucket <= T+1 provably contains fp64 top-16)
#pragma unroll
  for (int c = 0; c < 32; ++c) {
    if (bkt[c] <= Tp1) {
      int p = atomicAdd(&ctr[w], 1);
      if (p < BUFCAP) buf[w * BUFCAP + p] = (unsigned short)(c * 64 + lane);
    }
  }
  __syncthreads();

  int n = min(ctr[w], BUFCAP);
  double txd = (double)tx, tyd = (double)ty, tzd = (double)tz;

  if (n <= 64) {
    // Phase D: fp64 keys (bit-match numpy f64 ((dx^2+dy^2)+dz^2)),
    // 64-wide bitonic by (d2bits, idx); lanes 0..15 emit.
    unsigned long long gb = 0xFFFFFFFFFFFFFFFFull;
    int gj = 0x40000000 + lane;
    if (lane < n) {
      int j = buf[w * BUFCAP + lane];
      if (j != ti) {
        float4 q = pos4[j];
        double dx = __dsub_rn(txd, (double)q.x);
        double dy = __dsub_rn(tyd, (double)q.y);
        double dz = __dsub_rn(tzd, (double)q.z);
        double d2 = __dadd_rn(__dadd_rn(__dmul_rn(dx, dx), __dmul_rn(dy, dy)),
                              __dmul_rn(dz, dz));
        gb = (unsigned long long)__double_as_longlong(d2);
        gj = j;
      }
    }
    for (int k = 2; k <= 64; k <<= 1) {
      for (int jj = k >> 1; jj > 0; jj >>= 1) {
        unsigned long long ob = __shfl_xor(gb, jj);
        int oj = __shfl_xor(gj, jj);
        bool keepmin = (((lane & k) == 0) == ((lane & jj) == 0));
        bool less = (ob < gb) || (ob == gb && oj < gj);
        if (keepmin == less) { gb = ob; gj = oj; }
      }
    }
    if (lane < KNBR) nbr[(size_t)gi * KNBR + lane] = gj;
  } else {
    // rare fallback: extraction over buffered set (n <= 512)
    unsigned long long kb2[8];
    int id2[8];
#pragma unroll
    for (int r = 0; r < 8; ++r) {
      int e = r * 64 + lane;
      kb2[r] = 0xFFFFFFFFFFFFFFFFull;
      id2[r] = 0x40000000 + e;
      if (e < n) {
        int j = buf[w * BUFCAP + e];
        if (j != ti) {
          float4 q = pos4[j];
          double dx = __dsub_rn(txd, (double)q.x);
          double dy = __dsub_rn(tyd, (double)q.y);
          double dz = __dsub_rn(tzd, (double)q.z);
          double d2 = __dadd_rn(__dadd_rn(__dmul_rn(dx, dx), __dmul_rn(dy, dy)),
                                __dmul_rn(dz, dz));
          kb2[r] = (unsigned long long)__double_as_longlong(d2);
          id2[r] = j;
        }
      }
    }
    for (int r = 0; r < KNBR; ++r) {
      unsigned long long lb = kb2[0];
      int lj = id2[0];
#pragma unroll
      for (int c = 1; c < 8; ++c)
        if (kb2[c] < lb || (kb2[c] == lb && id2[c] < lj)) {
          lb = kb2[c]; lj = id2[c];
        }
      unsigned long long gb2 = lb;
      int gj2 = lj;
#pragma unroll
      for (int d = 32; d >= 1; d >>= 1) {
        unsigned long long ob = __shfl_xor(gb2, d);
        int oj = __shfl_xor(gj2, d);
        if (ob < gb2 || (ob == gb2 && oj < gj2)) { gb2 = ob; gj2 = oj; }
      }
#pragma unroll
      for (int c = 0; c < 8; ++c)
        if (id2[c] == gj2) kb2[c] = 0xFFFFFFFFFFFFFFFFull;
      if (lane == 0) nbr[(size_t)gi * KNBR + r] = gj2;
    }
  }
}

// ---------------------------------------------------------------------------
// edge: per target (1 wave, lane = channel): logits via precomputed A2/S2/WP2,
// delta via W_pos; 17-way softmax + weighted sum, self loop last.
// ---------------------------------------------------------------------------
__global__ __launch_bounds__(256) void edge_kernel(
    const float* __restrict__ pos, const int* __restrict__ nbr,
    const float* __restrict__ A2, const float* __restrict__ S2,
    const float* __restrict__ V, const float* __restrict__ WP2,
    const float* __restrict__ bbv, const float* __restrict__ Wpos,
    const float* __restrict__ bpos, float* __restrict__ out) {
  int t = threadIdx.x, w = t >> 6, c = t & 63;
  int gi = blockIdx.x * 4 + w;
  int cloudbase = gi & ~(NPC - 1);
  float pix = pos[(size_t)gi * 3], piy = pos[(size_t)gi * 3 + 1],
        piz = pos[(size_t)gi * 3 + 2];
  float a2 = A2[(size_t)gi * 64 + c];
  float wp0 = WP2[c], wp1 = WP2[64 + c], wp2 = WP2[128 + c], bbc = bbv[c];
  float u0 = Wpos[c], u1 = Wpos[64 + c], u2 = Wpos[128 + c], bpc = bpos[c];

  float lg[17], vl[17];
#pragma unroll
  for (int e = 0; e < 17; ++e) {
    int j = (e < 16) ? nbr[(size_t)gi * KNBR + e] : (gi & (NPC - 1));
    int jg = cloudbase + j;
    float dx = pix - pos[(size_t)jg * 3];
    float dy = piy - pos[(size_t)jg * 3 + 1];
    float dz = piz - pos[(size_t)jg * 3 + 2];
    float s2 = S2[(size_t)jg * 64 + c];
    float v = V[(size_t)jg * 64 + c];
    lg[e] = a2 - s2 + dx * wp0 + dy * wp1 + dz * wp2 + bbc;
    vl[e] = v + dx * u0 + dy * u1 + dz * u2 + bpc;
  }
  float mx = lg[0];
#pragma unroll
  for (int e = 1; e < 17; ++e) mx = fmaxf(mx, lg[e]);
  float den = 0.f, acc = 0.f;
#pragma unroll
  for (int e = 0; e < 17; ++e) {
    float wgt = __expf(lg[e] - mx);
    den += wgt;
    acc += wgt * vl[e];
  }
  out[(size_t)gi * 64 + c] = acc / den;
}

// ---------------------------------------------------------------------------
extern "C" void kernel_launch(void* const* d_in, const int* in_sizes, int n_in,
                              void* d_out, int out_size, void* d_ws, size_t ws_size,
                              hipStream_t stream) {
  const float* x     = (const float*)d_in[0];
  const float* pos   = (const float*)d_in[1];
  // d_in[2] = batch (contiguous equal clouds; unused)
  const float* Wpos  = (const float*)d_in[3];
  const float* bpos  = (const float*)d_in[4];
  const float* Wattn = (const float*)d_in[5];
  const float* battn = (const float*)d_in[6];
  const float* Wval  = (const float*)d_in[7];
  const float* Wsrc  = (const float*)d_in[8];
  const float* Wdst  = (const float*)d_in[9];

  float* ws  = (float*)d_ws;
  float* A2  = ws;                       // 32768*64
  float* S2  = A2 + (size_t)NPTS * 64;   // 32768*64
  float* V   = S2 + (size_t)NPTS * 64;   // 32768*64
  float* WP2 = V + (size_t)NPTS * 64;    // 3*64
  float* bb  = WP2 + 192;                // 64
  int*   nbr = (int*)(bb + 64);          // 32768*16 ints
  float* out = (float*)d_out;

  fused1_kernel<<<NGEMM + NKNN + 1, 1024, 0, stream>>>(
      pos, x, Wpos, bpos, Wattn, battn, Wval, Wsrc, Wdst,
      nbr, A2, S2, V, WP2, bb);
  edge_kernel<<<NPTS / 4, 256, 0, stream>>>(pos, nbr, A2, S2, V, WP2, bb,
                                            Wpos, bpos, out);
}

// Round 7
// 224.018 us; speedup vs baseline: 2.5351x; 1.0425x over previous
//
#include <hip/hip_runtime.h>
#include <math.h>

// Problem constants (fixed by reference)
#define BBATCH 16
#define NPC    2048          // points per cloud
#define KNBR   16            // knn k (self appended -> 17 edges)
#define NPTS   (BBATCH*NPC)  // 32768
#define NGEMM  512           // gemm blocks (64 rows each)
#define NKNN   512           // knn blocks (64 targets each)
#define BUFCAP 512

// ---------------------------------------------------------------------------
// fused_gk: two independent block families (+1 prep block):
//   blocks 0..511    : V = x@Wval, A2 = (x@Wdst)@Wattn, S2 = (x@Wsrc)@Wattn
//                      (Hd/Hs chained in-block via LDS; 64 rows per block)
//   blocks 512..1023 : exact fp64 16-NN, 64 targets per 1024-thread block
//                      (pos staged once; atomic-free compaction; self kept in
//                       candidate set via count>=17, excluded only in re-rank)
//   block 1024       : WP2 = Wpos@Wattn, bb = bpos@Wattn + battn
// ---------------------------------------------------------------------------
__global__ __launch_bounds__(1024) void fused_gk_kernel(
    const float* __restrict__ pos, const float* __restrict__ x,
    const float* __restrict__ Wpos, const float* __restrict__ bpos,
    const float* __restrict__ Wattn, const float* __restrict__ battn,
    const float* __restrict__ Wval, const float* __restrict__ Wsrc,
    const float* __restrict__ Wdst,
    int* __restrict__ nbr, float* __restrict__ A2, float* __restrict__ S2,
    float* __restrict__ V, float* __restrict__ WP2, float* __restrict__ bb) {
  __shared__ __align__(16) char smem[65536];
  int t = threadIdx.x;
  int bid = blockIdx.x;
  int c = t & 63, g = t >> 6;

  if (bid == NGEMM + NKNN) {  // ---- prep-lite ----
    if (t < 64) {
      for (int r = 0; r < 3; ++r) {
        float a = 0.f;
        for (int d = 0; d < 64; ++d) a += Wpos[r * 64 + d] * Wattn[d * 64 + t];
        WP2[r * 64 + t] = a;
      }
      float a = battn[t];
      for (int d = 0; d < 64; ++d) a += bpos[d] * Wattn[d * 64 + t];
      bb[t] = a;
    }
    return;
  }

  if (bid < NGEMM) {
    // ---- gemm family: 64 rows per block ----
    float* R0 = (float*)smem;            // staging: Wdst / Wsrc / x
    float* R1 = (float*)(smem + 16384);  // Hd = Wdst@Wattn
    float* R2 = (float*)(smem + 32768);  // Hs = Wsrc@Wattn
    float* R3 = (float*)(smem + 49152);  // Wattn, then Wval
    float4* R04 = (float4*)R0;
    float4* R34 = (float4*)R3;

    R34[t] = ((const float4*)Wattn)[t];
    R04[t] = ((const float4*)Wdst)[t];
    __syncthreads();
    {
      float a0 = 0, a1 = 0, a2 = 0, a3 = 0;
      for (int k = 0; k < 64; ++k) {
        float w = R3[k * 64 + c];
        a0 += R0[(g * 4 + 0) * 64 + k] * w;
        a1 += R0[(g * 4 + 1) * 64 + k] * w;
        a2 += R0[(g * 4 + 2) * 64 + k] * w;
        a3 += R0[(g * 4 + 3) * 64 + k] * w;
      }
      R1[(g * 4 + 0) * 64 + c] = a0; R1[(g * 4 + 1) * 64 + c] = a1;
      R1[(g * 4 + 2) * 64 + c] = a2; R1[(g * 4 + 3) * 64 + c] = a3;
    }
    __syncthreads();
    R04[t] = ((const float4*)Wsrc)[t];
    __syncthreads();
    {
      float a0 = 0, a1 = 0, a2 = 0, a3 = 0;
      for (int k = 0; k < 64; ++k) {
        float w = R3[k * 64 + c];
        a0 += R0[(g * 4 + 0) * 64 + k] * w;
        a1 += R0[(g * 4 + 1) * 64 + k] * w;
        a2 += R0[(g * 4 + 2) * 64 + k] * w;
        a3 += R0[(g * 4 + 3) * 64 + k] * w;
      }
      R2[(g * 4 + 0) * 64 + c] = a0; R2[(g * 4 + 1) * 64 + c] = a1;
      R2[(g * 4 + 2) * 64 + c] = a2; R2[(g * 4 + 3) * 64 + c] = a3;
    }
    __syncthreads();
    R34[t] = ((const float4*)Wval)[t];
    R04[t] = ((const float4*)(x + (size_t)bid * 64 * 64))[t];
    __syncthreads();

    float v0 = 0, v1 = 0, v2 = 0, v3 = 0;
    float a0 = 0, a1 = 0, a2 = 0, a3 = 0;
    float s0 = 0, s1 = 0, s2 = 0, s3 = 0;
    const float4* xr0 = (const float4*)(R0 + (g * 4 + 0) * 64);
    const float4* xr1 = (const float4*)(R0 + (g * 4 + 1) * 64);
    const float4* xr2 = (const float4*)(R0 + (g * 4 + 2) * 64);
    const float4* xr3 = (const float4*)(R0 + (g * 4 + 3) * 64);
#pragma unroll 4
    for (int k4 = 0; k4 < 16; ++k4) {
      float4 q0 = xr0[k4], q1 = xr1[k4], q2 = xr2[k4], q3 = xr3[k4];
#pragma unroll
      for (int kk = 0; kk < 4; ++kk) {
        int k = k4 * 4 + kk;
        float wv = R3[k * 64 + c];
        float wa = R1[k * 64 + c];
        float ws = R2[k * 64 + c];
        float e0 = (kk == 0) ? q0.x : (kk == 1) ? q0.y : (kk == 2) ? q0.z : q0.w;
        float e1 = (kk == 0) ? q1.x : (kk == 1) ? q1.y : (kk == 2) ? q1.z : q1.w;
        float e2 = (kk == 0) ? q2.x : (kk == 1) ? q2.y : (kk == 2) ? q2.z : q2.w;
        float e3 = (kk == 0) ? q3.x : (kk == 1) ? q3.y : (kk == 2) ? q3.z : q3.w;
        v0 += e0 * wv; v1 += e1 * wv; v2 += e2 * wv; v3 += e3 * wv;
        a0 += e0 * wa; a1 += e1 * wa; a2 += e2 * wa; a3 += e3 * wa;
        s0 += e0 * ws; s1 += e1 * ws; s2 += e2 * ws; s3 += e3 * ws;
      }
    }
    size_t o0 = ((size_t)bid * 64 + g * 4 + 0) * 64 + c;
    V[o0] = v0; A2[o0] = a0; S2[o0] = s0;
    size_t o1 = o0 + 64;  V[o1] = v1; A2[o1] = a1; S2[o1] = s1;
    size_t o2 = o0 + 128; V[o2] = v2; A2[o2] = a2; S2[o2] = s2;
    size_t o3 = o0 + 192; V[o3] = v3; A2[o3] = a3; S2[o3] = s3;
    return;
  }

  // ---- knn family: 64 targets per block ----
  int kb = bid - NGEMM;  // 0..511
  float4* pos4 = (float4*)smem;                           // 32 KB
  unsigned short* buf = (unsigned short*)(smem + 32768);  // 16 KB (16w x 512)
  int cloud = kb >> 5;  // 32 blocks per cloud
  const float* pc = pos + (size_t)cloud * NPC * 3;
  for (int p = t; p < NPC; p += 1024)
    pos4[p] = make_float4(pc[3 * p], pc[3 * p + 1], pc[3 * p + 2], 0.f);
  __syncthreads();

  int w = g, lane = c;
  for (int u = 0; u < 4; ++u) {
    int lt = u * 16 + w;  // local target 0..63
    int gi = kb * 64 + lt;
    int ti = gi & (NPC - 1);
    float4 tp = pos4[ti];
    float tx = tp.x, ty = tp.y, tz = tp.z;

    // Phase A: fp32 d^2 -> exponent bucket (self lands in bucket 0, kept)
    int bkt[32];
#pragma unroll
    for (int cc = 0; cc < 32; ++cc) {
      int j = cc * 64 + lane;
      float4 q = pos4[j];
      float dx = tx - q.x, dy = ty - q.y, dz = tz - q.z;
      float d2 = dx * dx + dy * dy + dz * dz;
      int b = (int)(__float_as_uint(d2) >> 20) - 896;
      bkt[cc] = max(0, min(255, b));
    }

    // Phase B: smallest T with count(bkt<=T) >= 17 (16 real + self)
    int lo = 0, hi = 255;
    for (int it = 0; it < 8; ++it) {
      int mid = (lo + hi) >> 1;
      int cnt = 0;
#pragma unroll
      for (int cc = 0; cc < 32; ++cc)
        cnt += (int)__popcll(__ballot(bkt[cc] <= mid));
      if (cnt >= 17) hi = mid; else lo = mid + 1;
    }
    int Tp1 = min(hi + 1, 255);

    // Phase C: atomic-free compaction (ballot + mbcnt prefix)
    int base = 0;
#pragma unroll
    for (int cc = 0; cc < 32; ++cc) {
      bool f = (bkt[cc] <= Tp1);
      unsigned long long mm = __ballot(f);
      unsigned int pre = __builtin_amdgcn_mbcnt_hi(
          (unsigned)(mm >> 32), __builtin_amdgcn_mbcnt_lo((unsigned)mm, 0u));
      if (f) {
        int p = base + (int)pre;
        if (p < BUFCAP) buf[w * BUFCAP + p] = (unsigned short)(cc * 64 + lane);
      }
      base += (int)__popcll(mm);
    }
    int n = min(base, BUFCAP);
    double txd = (double)tx, tyd = (double)ty, tzd = (double)tz;

    if (n <= 64) {
      // fp64 exact keys (bit-match numpy f64 ((dx^2+dy^2)+dz^2)), bitonic-64
      unsigned long long gb = 0xFFFFFFFFFFFFFFFFull;
      int gj = 0x40000000 + lane;
      if (lane < n) {
        int j = buf[w * BUFCAP + lane];
        if (j != ti) {
          float4 q = pos4[j];
          double dx = __dsub_rn(txd, (double)q.x);
          double dy = __dsub_rn(tyd, (double)q.y);
          double dz = __dsub_rn(tzd, (double)q.z);
          double d2 = __dadd_rn(__dadd_rn(__dmul_rn(dx, dx), __dmul_rn(dy, dy)),
                                __dmul_rn(dz, dz));
          gb = (unsigned long long)__double_as_longlong(d2);
          gj = j;
        }
      }
      for (int k = 2; k <= 64; k <<= 1) {
        for (int jj = k >> 1; jj > 0; jj >>= 1) {
          unsigned long long ob = __shfl_xor(gb, jj);
          int oj = __shfl_xor(gj, jj);
          bool keepmin = (((lane & k) == 0) == ((lane & jj) == 0));
          bool less = (ob < gb) || (ob == gb && oj < gj);
          if (keepmin == less) { gb = ob; gj = oj; }
        }
      }
      if (lane < KNBR) nbr[(size_t)gi * KNBR + lane] = gj;
    } else {
      // rare fallback: extraction over buffered set (n <= 512)
      unsigned long long kb2[8];
      int id2[8];
#pragma unroll
      for (int r = 0; r < 8; ++r) {
        int e = r * 64 + lane;
        kb2[r] = 0xFFFFFFFFFFFFFFFFull;
        id2[r] = 0x40000000 + e;
        if (e < n) {
          int j = buf[w * BUFCAP + e];
          if (j != ti) {
            float4 q = pos4[j];
            double dx = __dsub_rn(txd, (double)q.x);
            double dy = __dsub_rn(tyd, (double)q.y);
            double dz = __dsub_rn(tzd, (double)q.z);
            double d2 = __dadd_rn(
                __dadd_rn(__dmul_rn(dx, dx), __dmul_rn(dy, dy)),
                __dmul_rn(dz, dz));
            kb2[r] = (unsigned long long)__double_as_longlong(d2);
            id2[r] = j;
          }
        }
      }
      for (int r = 0; r < KNBR; ++r) {
        unsigned long long lb = kb2[0];
        int lj = id2[0];
#pragma unroll
        for (int cc = 1; cc < 8; ++cc)
          if (kb2[cc] < lb || (kb2[cc] == lb && id2[cc] < lj)) {
            lb = kb2[cc]; lj = id2[cc];
          }
        unsigned long long gb2 = lb;
        int gj2 = lj;
#pragma unroll
        for (int d = 32; d >= 1; d >>= 1) {
          unsigned long long ob = __shfl_xor(gb2, d);
          int oj = __shfl_xor(gj2, d);
          if (ob < gb2 || (ob == gb2 && oj < gj2)) { gb2 = ob; gj2 = oj; }
        }
#pragma unroll
        for (int cc = 0; cc < 8; ++cc)
          if (id2[cc] == gj2) kb2[cc] = 0xFFFFFFFFFFFFFFFFull;
        if (lane == 0) nbr[(size_t)gi * KNBR + r] = gj2;
      }
    }
  }
}

// ---------------------------------------------------------------------------
// edge: per target (1 wave, lane = channel): logits via precomputed A2/S2/WP2,
// delta via W_pos; 17-way softmax + weighted sum, self loop last.
// (Unchanged from the R5 passing version.)
// ---------------------------------------------------------------------------
__global__ __launch_bounds__(256) void edge_kernel(
    const float* __restrict__ pos, const int* __restrict__ nbr,
    const float* __restrict__ A2, const float* __restrict__ S2,
    const float* __restrict__ V, const float* __restrict__ WP2,
    const float* __restrict__ bbv, const float* __restrict__ Wpos,
    const float* __restrict__ bpos, float* __restrict__ out) {
  int t = threadIdx.x, w = t >> 6, c = t & 63;
  int gi = blockIdx.x * 4 + w;
  int cloudbase = gi & ~(NPC - 1);
  float pix = pos[(size_t)gi * 3], piy = pos[(size_t)gi * 3 + 1],
        piz = pos[(size_t)gi * 3 + 2];
  float a2 = A2[(size_t)gi * 64 + c];
  float wp0 = WP2[c], wp1 = WP2[64 + c], wp2 = WP2[128 + c], bbc = bbv[c];
  float u0 = Wpos[c], u1 = Wpos[64 + c], u2 = Wpos[128 + c], bpc = bpos[c];

  float lg[17], vl[17];
#pragma unroll
  for (int e = 0; e < 17; ++e) {
    int j = (e < 16) ? nbr[(size_t)gi * KNBR + e] : (gi & (NPC - 1));
    int jg = cloudbase + j;
    float dx = pix - pos[(size_t)jg * 3];
    float dy = piy - pos[(size_t)jg * 3 + 1];
    float dz = piz - pos[(size_t)jg * 3 + 2];
    float s2 = S2[(size_t)jg * 64 + c];
    float v = V[(size_t)jg * 64 + c];
    lg[e] = a2 - s2 + dx * wp0 + dy * wp1 + dz * wp2 + bbc;
    vl[e] = v + dx * u0 + dy * u1 + dz * u2 + bpc;
  }
  float mx = lg[0];
#pragma unroll
  for (int e = 1; e < 17; ++e) mx = fmaxf(mx, lg[e]);
  float den = 0.f, acc = 0.f;
#pragma unroll
  for (int e = 0; e < 17; ++e) {
    float wgt = __expf(lg[e] - mx);
    den += wgt;
    acc += wgt * vl[e];
  }
  out[(size_t)gi * 64 + c] = acc / den;
}

// ---------------------------------------------------------------------------
extern "C" void kernel_launch(void* const* d_in, const int* in_sizes, int n_in,
                              void* d_out, int out_size, void* d_ws, size_t ws_size,
                              hipStream_t stream) {
  const float* x     = (const float*)d_in[0];
  const float* pos   = (const float*)d_in[1];
  // d_in[2] = batch (contiguous equal clouds; unused)
  const float* Wpos  = (const float*)d_in[3];
  const float* bpos  = (const float*)d_in[4];
  const float* Wattn = (const float*)d_in[5];
  const float* battn = (const float*)d_in[6];
  const float* Wval  = (const float*)d_in[7];
  const float* Wsrc  = (const float*)d_in[8];
  const float* Wdst  = (const float*)d_in[9];

  float* ws  = (float*)d_ws;
  float* A2  = ws;                       // 32768*64
  float* S2  = A2 + (size_t)NPTS * 64;   // 32768*64
  float* V   = S2 + (size_t)NPTS * 64;   // 32768*64
  float* WP2 = V + (size_t)NPTS * 64;    // 3*64
  float* bb  = WP2 + 192;                // 64
  int*   nbr = (int*)(bb + 64);          // 32768*16 ints
  float* out = (float*)d_out;

  fused_gk_kernel<<<NGEMM + NKNN + 1, 1024, 0, stream>>>(
      pos, x, Wpos, bpos, Wattn, battn, Wval, Wsrc, Wdst,
      nbr, A2, S2, V, WP2, bb);
  edge_kernel<<<NPTS / 4, 256, 0, stream>>>(pos, nbr, A2, S2, V, WP2, bb,
                                            Wpos, bpos, out);
}